// Round 3
// baseline (1787.747 us; speedup 1.0000x reference)
//
#include <hip/hip_runtime.h>
#include <hip/hip_bf16.h>

// Problem constants
constexpr int Ec = 1024;   // embed
constexpr int Hc = 16;     // heads
constexpr int Dc = 64;     // head dim
constexpr int Bc = 4;      // batch
constexpr int Sc = 1024;   // seq
constexpr int LDP = 68;    // padded LDS stride (floats); 68*4B: 16B-aligned rows, 68%32==4 breaks pow2 bank stride

// ---------------------------------------------------------------------------
// K1: fused QKV projection.  C[m, n] = X_sel[m,:] . W[n,:] + bias[n], n in [0,3072)
// n<1024 -> query (scaled by 1/8), <2048 -> key, else value.
// Output layout (3, B, H, S, D) into ws.
// ---------------------------------------------------------------------------
__global__ __launch_bounds__(256) void k_qkv(
    const float* __restrict__ q_in, const float* __restrict__ k_in,
    const float* __restrict__ v_in, const float* __restrict__ w,
    const float* __restrict__ bias, float* __restrict__ qkv)
{
  __shared__ float As[32][LDP];   // [k][m] transposed
  __shared__ float Bs[32][LDP];   // [k][n] transposed
  const int tid = threadIdx.x;
  const int m0 = blockIdx.x * 64;          // over B*S
  const int n0 = blockIdx.y * 64;          // over 3E
  const int third = n0 >> 10;
  const float* x = (third == 0) ? q_in : (third == 1) ? k_in : v_in;
  const int b  = m0 >> 10;
  const int s0 = m0 & 1023;
  const int h  = (n0 & 1023) >> 6;         // BN==D so h fixed per block
  const float scale = (third == 0) ? 0.125f : 1.0f;

  const int tm = (tid & 15) << 2;
  const int tn = (tid >> 4) << 2;
  float c[4][4] = {};

  const float* xbase = x + (size_t)m0 * Ec;
  const float* wbase = w + (size_t)n0 * Ec;

  for (int k0 = 0; k0 < Ec; k0 += 32) {
#pragma unroll
    for (int i = 0; i < 2; ++i) {
      int lin = tid + i * 256;
      int row = lin >> 3, f4 = (lin & 7) << 2;
      float4 av = *reinterpret_cast<const float4*>(xbase + (size_t)row * Ec + k0 + f4);
      As[f4 + 0][row] = av.x; As[f4 + 1][row] = av.y;
      As[f4 + 2][row] = av.z; As[f4 + 3][row] = av.w;
      float4 bv = *reinterpret_cast<const float4*>(wbase + (size_t)row * Ec + k0 + f4);
      Bs[f4 + 0][row] = bv.x; Bs[f4 + 1][row] = bv.y;
      Bs[f4 + 2][row] = bv.z; Bs[f4 + 3][row] = bv.w;
    }
    __syncthreads();
#pragma unroll
    for (int k = 0; k < 32; ++k) {
      float4 a4 = *reinterpret_cast<const float4*>(&As[k][tm]);
      float4 b4 = *reinterpret_cast<const float4*>(&Bs[k][tn]);
      float a[4]  = {a4.x, a4.y, a4.z, a4.w};
      float bb[4] = {b4.x, b4.y, b4.z, b4.w};
#pragma unroll
      for (int i = 0; i < 4; ++i)
#pragma unroll
        for (int j = 0; j < 4; ++j)
          c[i][j] = fmaf(a[i], bb[j], c[i][j]);
    }
    __syncthreads();
  }

  float bq[4];
#pragma unroll
  for (int j = 0; j < 4; ++j) bq[j] = bias[n0 + tn + j];
  float* outb = qkv + (size_t)third * (Bc * Hc * Sc * Dc)
                    + ((size_t)(b * Hc + h) * Sc) * Dc;
#pragma unroll
  for (int i = 0; i < 4; ++i) {
    float4 o;
    o.x = (c[i][0] + bq[0]) * scale;
    o.y = (c[i][1] + bq[1]) * scale;
    o.z = (c[i][2] + bq[2]) * scale;
    o.w = (c[i][3] + bq[3]) * scale;
    *reinterpret_cast<float4*>(outb + (size_t)(s0 + tm + i) * Dc + tn) = o;
  }
}

// ---------------------------------------------------------------------------
// K2: flash attention per (b, h, 64-row q-tile).  Writes normalized ctx
// (B,H,S,D) plus per-row running max m and denom l for the avg-weights pass.
// ---------------------------------------------------------------------------
__global__ __launch_bounds__(256) void k_flash(
    const float* __restrict__ qkv, float* __restrict__ ctx,
    float* __restrict__ mrow, float* __restrict__ lrow)
{
  __shared__ float Qt[Dc][LDP];   // [d][qrow]
  __shared__ float Kt[Dc][LDP];   // [d][krow]
  __shared__ float Vs[64][LDP];   // [krow][d]
  __shared__ float Ps[64][LDP];   // [krow][qrow]
  __shared__ float redM[64][5];
  __shared__ float redS[64][5];

  const int tid = threadIdx.x;
  const int lane = tid & 63;
  const int wave = tid >> 6;
  const int s0 = blockIdx.x * 64;
  const int h = blockIdx.y, b = blockIdx.z;
  const int tm = (tid & 15) << 2;
  const int tn = (tid >> 4) << 2;

  const float* Q = qkv;
  const float* K = qkv + (size_t)Bc * Hc * Sc * Dc;
  const float* V = K + (size_t)Bc * Hc * Sc * Dc;
  const size_t bh = (size_t)(b * Hc + h) * Sc;

  // stage Q transposed (consumed after first __syncthreads below)
#pragma unroll
  for (int i = 0; i < 4; ++i) {
    int lin = tid + i * 256;
    int row = lin >> 4, f4 = (lin & 15) << 2;
    float4 v = *reinterpret_cast<const float4*>(Q + (bh + s0 + row) * Dc + f4);
    Qt[f4 + 0][row] = v.x; Qt[f4 + 1][row] = v.y;
    Qt[f4 + 2][row] = v.z; Qt[f4 + 3][row] = v.w;
  }

  float o[4][4] = {};
  float m_r[4], l_r[4];
#pragma unroll
  for (int i = 0; i < 4; ++i) { m_r[i] = -1e30f; l_r[i] = 0.f; }

  for (int kt = 0; kt < 16; ++kt) {
    const int k0 = kt * 64;
    float4 kv[4], vv[4];
#pragma unroll
    for (int i = 0; i < 4; ++i) {
      int lin = tid + i * 256;
      int row = lin >> 4, f4 = (lin & 15) << 2;
      kv[i] = *reinterpret_cast<const float4*>(K + (bh + k0 + row) * Dc + f4);
      vv[i] = *reinterpret_cast<const float4*>(V + (bh + k0 + row) * Dc + f4);
    }
    __syncthreads();          // prev iter's Kt/Vs/Ps reads done; Qt stores done
#pragma unroll
    for (int i = 0; i < 4; ++i) {
      int lin = tid + i * 256;
      int row = lin >> 4, f4 = (lin & 15) << 2;
      Kt[f4 + 0][row] = kv[i].x; Kt[f4 + 1][row] = kv[i].y;
      Kt[f4 + 2][row] = kv[i].z; Kt[f4 + 3][row] = kv[i].w;
      *reinterpret_cast<float4*>(&Vs[row][f4]) = vv[i];
    }
    __syncthreads();

    // scores: s = Q . K^T  (inner dim d)
    float c[4][4] = {};
#pragma unroll
    for (int d = 0; d < Dc; ++d) {
      float4 a4 = *reinterpret_cast<const float4*>(&Qt[d][tm]);
      float4 b4 = *reinterpret_cast<const float4*>(&Kt[d][tn]);
      float a[4]  = {a4.x, a4.y, a4.z, a4.w};
      float bb[4] = {b4.x, b4.y, b4.z, b4.w};
#pragma unroll
      for (int i = 0; i < 4; ++i)
#pragma unroll
        for (int j = 0; j < 4; ++j)
          c[i][j] = fmaf(a[i], bb[j], c[i][j]);
    }

    // row max: wave shuffle over the 4 col-groups, LDS across 4 waves
#pragma unroll
    for (int i = 0; i < 4; ++i) {
      float v = fmaxf(fmaxf(c[i][0], c[i][1]), fmaxf(c[i][2], c[i][3]));
      v = fmaxf(v, __shfl_xor(v, 16));
      v = fmaxf(v, __shfl_xor(v, 32));
      if ((lane >> 4) == 0) redM[tm + i][wave] = v;
    }
    __syncthreads();
    float mnew[4], sc[4];
#pragma unroll
    for (int i = 0; i < 4; ++i) {
      float mt = fmaxf(fmaxf(redM[tm + i][0], redM[tm + i][1]),
                       fmaxf(redM[tm + i][2], redM[tm + i][3]));
      mnew[i] = fmaxf(m_r[i], mt);
      sc[i] = __expf(m_r[i] - mnew[i]);
      m_r[i] = mnew[i];
    }
    // p = exp(s - m), store P^T to LDS, row sums
#pragma unroll
    for (int i = 0; i < 4; ++i) {
      float s = 0.f;
#pragma unroll
      for (int j = 0; j < 4; ++j) {
        float p = __expf(c[i][j] - mnew[i]);
        Ps[tn + j][tm + i] = p;
        s += p;
      }
      s += __shfl_xor(s, 16);
      s += __shfl_xor(s, 32);
      if ((lane >> 4) == 0) redS[tm + i][wave] = s;
    }
    __syncthreads();          // covers Ps stores + redS
#pragma unroll
    for (int i = 0; i < 4; ++i) {
      float st = redS[tm + i][0] + redS[tm + i][1]
               + redS[tm + i][2] + redS[tm + i][3];
      l_r[i] = l_r[i] * sc[i] + st;
#pragma unroll
      for (int j = 0; j < 4; ++j) o[i][j] *= sc[i];
    }
    // PV: o += P . V  (inner dim k)
#pragma unroll
    for (int kk = 0; kk < 64; ++kk) {
      float4 a4 = *reinterpret_cast<const float4*>(&Ps[kk][tm]);
      float4 b4 = *reinterpret_cast<const float4*>(&Vs[kk][tn]);
      float a[4]  = {a4.x, a4.y, a4.z, a4.w};
      float bb[4] = {b4.x, b4.y, b4.z, b4.w};
#pragma unroll
      for (int i = 0; i < 4; ++i)
#pragma unroll
        for (int j = 0; j < 4; ++j)
          o[i][j] = fmaf(a[i], bb[j], o[i][j]);
    }
  }

#pragma unroll
  for (int i = 0; i < 4; ++i) {
    float inv = 1.0f / l_r[i];
    float4 ov;
    ov.x = o[i][0] * inv; ov.y = o[i][1] * inv;
    ov.z = o[i][2] * inv; ov.w = o[i][3] * inv;
    *reinterpret_cast<float4*>(ctx + (bh + s0 + tm + i) * Dc + tn) = ov;
  }
  if (tid < 16) {
#pragma unroll
    for (int i = 0; i < 4; ++i) {
      mrow[bh + s0 + tm + i] = m_r[i];
      lrow[bh + s0 + tm + i] = l_r[i];
    }
  }
}

// ---------------------------------------------------------------------------
// K3: out projection. A = ctx gathered from (B,H,S,D) as (B,S,E); W (E,E).
// ---------------------------------------------------------------------------
__global__ __launch_bounds__(256) void k_outproj(
    const float* __restrict__ ctx, const float* __restrict__ w,
    const float* __restrict__ bias, float* __restrict__ out)
{
  __shared__ float As[32][LDP];
  __shared__ float Bs[32][LDP];
  const int tid = threadIdx.x;
  const int m0 = blockIdx.x * 64;
  const int n0 = blockIdx.y * 64;
  const int b  = m0 >> 10;
  const int s0 = m0 & 1023;
  const int tm = (tid & 15) << 2;
  const int tn = (tid >> 4) << 2;
  float c[4][4] = {};
  const float* wbase = w + (size_t)n0 * Ec;
  const float* ctxb = ctx + (size_t)b * (Hc * Sc * Dc);

  for (int k0 = 0; k0 < Ec; k0 += 32) {
#pragma unroll
    for (int i = 0; i < 2; ++i) {
      int lin = tid + i * 256;
      int row = lin >> 3, f4 = (lin & 7) << 2;
      int e = k0 + f4;   // 16-float chunk never crosses a head boundary
      float4 av = *reinterpret_cast<const float4*>(
          ctxb + ((size_t)(e >> 6) * Sc + (s0 + row)) * Dc + (e & 63));
      As[f4 + 0][row] = av.x; As[f4 + 1][row] = av.y;
      As[f4 + 2][row] = av.z; As[f4 + 3][row] = av.w;
      float4 bv = *reinterpret_cast<const float4*>(wbase + (size_t)row * Ec + k0 + f4);
      Bs[f4 + 0][row] = bv.x; Bs[f4 + 1][row] = bv.y;
      Bs[f4 + 2][row] = bv.z; Bs[f4 + 3][row] = bv.w;
    }
    __syncthreads();
#pragma unroll
    for (int k = 0; k < 32; ++k) {
      float4 a4 = *reinterpret_cast<const float4*>(&As[k][tm]);
      float4 b4 = *reinterpret_cast<const float4*>(&Bs[k][tn]);
      float a[4]  = {a4.x, a4.y, a4.z, a4.w};
      float bb[4] = {b4.x, b4.y, b4.z, b4.w};
#pragma unroll
      for (int i = 0; i < 4; ++i)
#pragma unroll
        for (int j = 0; j < 4; ++j)
          c[i][j] = fmaf(a[i], bb[j], c[i][j]);
    }
    __syncthreads();
  }

  float bq[4];
#pragma unroll
  for (int j = 0; j < 4; ++j) bq[j] = bias[n0 + tn + j];
#pragma unroll
  for (int i = 0; i < 4; ++i) {
    float4 o;
    o.x = c[i][0] + bq[0]; o.y = c[i][1] + bq[1];
    o.z = c[i][2] + bq[2]; o.w = c[i][3] + bq[3];
    *reinterpret_cast<float4*>(out + (size_t)(m0 + tm + i) * Ec + n0 + tn) = o;
  }
}

// ---------------------------------------------------------------------------
// K4: head-averaged attention weights * gate (unnormalized).
// Block = (b, 64-row q-tile, 256-col k-chunk). Head loop inside; w recomputed
// as exp(q.k - m)/l using m,l from K2. Writes avg*gate into out1.
// ---------------------------------------------------------------------------
__global__ __launch_bounds__(256) void k_avggate(
    const float* __restrict__ qkv, const float* __restrict__ mrow,
    const float* __restrict__ lrow, const float* __restrict__ gate,
    float* __restrict__ out1)
{
  __shared__ float Qt[Dc][LDP];
  __shared__ float Kt[Dc][LDP];
  const int tid = threadIdx.x;
  const int c0 = blockIdx.x * 256;
  const int s0 = blockIdx.y * 64;
  const int b  = blockIdx.z;
  const int tm = (tid & 15) << 2;
  const int tn = (tid >> 4) << 2;

  const float* Q = qkv;
  const float* K = qkv + (size_t)Bc * Hc * Sc * Dc;

  float avg[4][4][4] = {};   // [kt][i][j]

  for (int h = 0; h < Hc; ++h) {
    const size_t bh = (size_t)(b * Hc + h) * Sc;
    float mh[4], li[4];
#pragma unroll
    for (int i = 0; i < 4; ++i) {
      mh[i] = mrow[bh + s0 + tm + i];
      li[i] = 0.0625f / lrow[bh + s0 + tm + i];   // 1/16 head mean folded in
    }
    __syncthreads();     // prev h's compute reads of Qt done
#pragma unroll
    for (int i = 0; i < 4; ++i) {
      int lin = tid + i * 256;
      int row = lin >> 4, f4 = (lin & 15) << 2;
      float4 v = *reinterpret_cast<const float4*>(Q + (bh + s0 + row) * Dc + f4);
      Qt[f4 + 0][row] = v.x; Qt[f4 + 1][row] = v.y;
      Qt[f4 + 2][row] = v.z; Qt[f4 + 3][row] = v.w;
    }
    for (int kt = 0; kt < 4; ++kt) {
      const int k0 = c0 + kt * 64;
      float4 kvr[4];
#pragma unroll
      for (int i = 0; i < 4; ++i) {
        int lin = tid + i * 256;
        int row = lin >> 4, f4 = (lin & 15) << 2;
        kvr[i] = *reinterpret_cast<const float4*>(K + (bh + k0 + row) * Dc + f4);
      }
      __syncthreads();   // prev kt's Kt reads done; Qt stores done (kt==0)
#pragma unroll
      for (int i = 0; i < 4; ++i) {
        int lin = tid + i * 256;
        int row = lin >> 4, f4 = (lin & 15) << 2;
        Kt[f4 + 0][row] = kvr[i].x; Kt[f4 + 1][row] = kvr[i].y;
        Kt[f4 + 2][row] = kvr[i].z; Kt[f4 + 3][row] = kvr[i].w;
      }
      __syncthreads();
      float c[4][4] = {};
#pragma unroll
      for (int d = 0; d < Dc; ++d) {
        float4 a4 = *reinterpret_cast<const float4*>(&Qt[d][tm]);
        float4 b4 = *reinterpret_cast<const float4*>(&Kt[d][tn]);
        float a[4]  = {a4.x, a4.y, a4.z, a4.w};
        float bb[4] = {b4.x, b4.y, b4.z, b4.w};
#pragma unroll
        for (int i = 0; i < 4; ++i)
#pragma unroll
          for (int j = 0; j < 4; ++j)
            c[i][j] = fmaf(a[i], bb[j], c[i][j]);
      }
#pragma unroll
      for (int i = 0; i < 4; ++i)
#pragma unroll
        for (int j = 0; j < 4; ++j)
          avg[kt][i][j] += __expf(c[i][j] - mh[i]) * li[i];
    }
  }

#pragma unroll
  for (int kt = 0; kt < 4; ++kt) {
#pragma unroll
    for (int i = 0; i < 4; ++i) {
      size_t base = ((size_t)b * Sc + s0 + tm + i) * Sc + c0 + kt * 64 + tn;
      float4 g = *reinterpret_cast<const float4*>(gate + base);
      float4 ov;
      ov.x = avg[kt][i][0] * g.x; ov.y = avg[kt][i][1] * g.y;
      ov.z = avg[kt][i][2] * g.z; ov.w = avg[kt][i][3] * g.w;
      *reinterpret_cast<float4*>(out1 + base) = ov;
    }
  }
}

// ---------------------------------------------------------------------------
// K5: in-place row renormalization of gated weights: x / (sum(x) + 1e-12)
// ---------------------------------------------------------------------------
__global__ __launch_bounds__(256) void k_renorm(float* __restrict__ out1)
{
  __shared__ float wsum[4];
  const int tid = threadIdx.x;
  float* row = out1 + (size_t)blockIdx.x * Sc;
  float4 v = *reinterpret_cast<const float4*>(row + tid * 4);
  float s = v.x + v.y + v.z + v.w;
#pragma unroll
  for (int off = 1; off < 64; off <<= 1) s += __shfl_xor(s, off);
  if ((tid & 63) == 0) wsum[tid >> 6] = s;
  __syncthreads();
  float inv = 1.0f / (wsum[0] + wsum[1] + wsum[2] + wsum[3] + 1e-12f);
  v.x *= inv; v.y *= inv; v.z *= inv; v.w *= inv;
  *reinterpret_cast<float4*>(row + tid * 4) = v;
}

// ---------------------------------------------------------------------------
extern "C" void kernel_launch(void* const* d_in, const int* in_sizes, int n_in,
                              void* d_out, int out_size, void* d_ws, size_t ws_size,
                              hipStream_t stream) {
  const float* query = (const float*)d_in[0];
  const float* key   = (const float*)d_in[1];
  const float* value = (const float*)d_in[2];
  const float* gate  = (const float*)d_in[3];
  const float* w_in  = (const float*)d_in[4];
  const float* b_in  = (const float*)d_in[5];
  const float* w_out = (const float*)d_in[6];
  const float* b_out = (const float*)d_in[7];

  float* out0 = (float*)d_out;                       // attn_output (B,S,E)
  float* out1 = out0 + (size_t)Bc * Sc * Ec;         // gated (B,S,S)

  float* ws   = (float*)d_ws;
  float* qkv  = ws;                                  // 3 * B*H*S*D
  float* ctx  = ws + (size_t)3 * Bc * Hc * Sc * Dc;  // B*H*S*D
  float* mrow = ctx + (size_t)Bc * Hc * Sc * Dc;     // B*H*S
  float* lrow = mrow + (size_t)Bc * Hc * Sc;         // B*H*S

  hipLaunchKernelGGL(k_qkv, dim3(64, 48), dim3(256), 0, stream,
                     query, key, value, w_in, b_in, qkv);
  hipLaunchKernelGGL(k_flash, dim3(16, 16, 4), dim3(256), 0, stream,
                     qkv, ctx, mrow, lrow);
  hipLaunchKernelGGL(k_outproj, dim3(64, 16), dim3(256), 0, stream,
                     ctx, w_out, b_out, out0);
  hipLaunchKernelGGL(k_avggate, dim3(4, 16, 4), dim3(256), 0, stream,
                     qkv, mrow, lrow, gate, out1);
  hipLaunchKernelGGL(k_renorm, dim3(Bc * Sc), dim3(256), 0, stream, out1);
}

// Round 5
// 348.184 us; speedup vs baseline: 5.1345x; 5.1345x over previous
//
#include <hip/hip_runtime.h>

typedef unsigned short ushortT;
typedef __attribute__((ext_vector_type(8))) short bf16x8;
typedef __attribute__((ext_vector_type(4))) float f32x4;

constexpr int Ec = 1024;   // embed
constexpr int Hc = 16;     // heads
constexpr int Dc = 64;     // head dim
constexpr int Bc = 4;      // batch
constexpr int Sc = 1024;   // seq
constexpr int XN = Bc * Sc * Ec;          // 4194304 (elements of one B,S,E tensor)
constexpr int LDW = 72;    // LDS row stride in bf16 (144B: 16B-aligned, good bank spread)

#define MFMA_BF16 __builtin_amdgcn_mfma_f32_16x16x32_bf16

__device__ __forceinline__ ushortT f2bf(float f) {
  union { float f; unsigned int u; } x{f};
  unsigned int r = x.u + 0x7fffu + ((x.u >> 16) & 1u);   // RNE
  return (ushortT)(r >> 16);
}

// ---------------------------------------------------------------------------
// K0: cast fp32 inputs/weights -> bf16 workspace copies.
// seg: 0=query 1=key 2=value 3=in_proj_w 4=out_proj_w
// ---------------------------------------------------------------------------
struct US8 { ushortT u[8]; };

__global__ __launch_bounds__(256) void k_cast(
    const float* __restrict__ q, const float* __restrict__ k,
    const float* __restrict__ v, const float* __restrict__ wi,
    const float* __restrict__ wo,
    ushortT* __restrict__ oq, ushortT* __restrict__ ok,
    ushortT* __restrict__ ov, ushortT* __restrict__ owi,
    ushortT* __restrict__ owo)
{
  const int seg = blockIdx.y;
  const float* src; ushortT* dst; int n;
  if      (seg == 0) { src = q;  dst = oq;  n = XN; }
  else if (seg == 1) { src = k;  dst = ok;  n = XN; }
  else if (seg == 2) { src = v;  dst = ov;  n = XN; }
  else if (seg == 3) { src = wi; dst = owi; n = 3 * Ec * Ec; }
  else               { src = wo; dst = owo; n = Ec * Ec; }
  int base = (blockIdx.x * 256 + threadIdx.x) * 8;
  if (base >= n) return;
  float4 a = *reinterpret_cast<const float4*>(src + base);
  float4 b = *reinterpret_cast<const float4*>(src + base + 4);
  US8 o;
  o.u[0] = f2bf(a.x); o.u[1] = f2bf(a.y); o.u[2] = f2bf(a.z); o.u[3] = f2bf(a.w);
  o.u[4] = f2bf(b.x); o.u[5] = f2bf(b.y); o.u[6] = f2bf(b.z); o.u[7] = f2bf(b.w);
  *reinterpret_cast<US8*>(dst + base) = o;
}

// ---------------------------------------------------------------------------
// K1: QKV projection, bf16 MFMA. C[m,n] = X[m,:] . W[n,:] + bias[n]
// M=4096 (B*S), N=3072 (3E), K=1024. Block 128x128, BK=64, 4 waves (2x2),
// each wave 64x64 = 4x4 fragments of 16x16x32.
// Output (3,B,H,S,D) bf16, q scaled by 1/8.
// ---------------------------------------------------------------------------
__global__ __launch_bounds__(256) void k_qkv_mfma(
    const ushortT* __restrict__ xq, const ushortT* __restrict__ xk,
    const ushortT* __restrict__ xv, const ushortT* __restrict__ wi,
    const float* __restrict__ bias, ushortT* __restrict__ qkv)
{
  __shared__ __align__(16) ushortT As[128][LDW];
  __shared__ __align__(16) ushortT Bs[128][LDW];
  const int tid = threadIdx.x;
  const int lane = tid & 63, wid = tid >> 6;
  const int wm = wid >> 1, wn = wid & 1;
  const int li = lane & 15, gi = lane >> 4;
  const int m0 = blockIdx.x * 128, n0 = blockIdx.y * 128;
  const int third = n0 >> 10;
  const ushortT* x = (third == 0) ? xq : (third == 1) ? xk : xv;

  f32x4 acc[4][4] = {};

  for (int k0 = 0; k0 < 1024; k0 += 64) {
    __syncthreads();
#pragma unroll
    for (int i = 0; i < 4; ++i) {
      int c = tid + i * 256;                 // 0..1023
      int row = c >> 3, col = (c & 7) * 8;
      *reinterpret_cast<uint4*>(&As[row][col]) =
          *reinterpret_cast<const uint4*>(x + (size_t)(m0 + row) * 1024 + k0 + col);
      *reinterpret_cast<uint4*>(&Bs[row][col]) =
          *reinterpret_cast<const uint4*>(wi + (size_t)(n0 + row) * 1024 + k0 + col);
    }
    __syncthreads();
#pragma unroll
    for (int ks = 0; ks < 2; ++ks) {
      bf16x8 a[4], b[4];
#pragma unroll
      for (int t = 0; t < 4; ++t) {
        a[t] = *reinterpret_cast<const bf16x8*>(&As[wm * 64 + t * 16 + li][ks * 32 + gi * 8]);
        b[t] = *reinterpret_cast<const bf16x8*>(&Bs[wn * 64 + t * 16 + li][ks * 32 + gi * 8]);
      }
#pragma unroll
      for (int mi = 0; mi < 4; ++mi)
#pragma unroll
        for (int ni = 0; ni < 4; ++ni)
          acc[mi][ni] = MFMA_BF16(a[mi], b[ni], acc[mi][ni], 0, 0, 0);
    }
  }

  const float scale = (third == 0) ? 0.125f : 1.0f;
#pragma unroll
  for (int ni = 0; ni < 4; ++ni) {
    int n = n0 + wn * 64 + ni * 16 + li;
    float bv = bias[n];
    int h = (n >> 6) & 15, d = n & 63;
#pragma unroll
    for (int mi = 0; mi < 4; ++mi)
#pragma unroll
      for (int r = 0; r < 4; ++r) {
        int m = m0 + wm * 64 + mi * 16 + gi * 4 + r;
        int b_ = m >> 10, s = m & 1023;
        size_t o = ((((size_t)third * Bc + b_) * Hc + h) * Sc + s) * Dc + d;
        qkv[o] = f2bf((acc[mi][ni][r] + bv) * scale);
      }
  }
}

// ---------------------------------------------------------------------------
// K2: flash attention, bf16 MFMA. Block = (qtile 64, h, b), 4 waves; wave w
// owns q rows [16w,16w+16). Scores C[q][k]: wave-local softmax via shfl.
// P and V use a per-tile k-permutation k' = 4*(k&15)+(k>>4) consistently.
// Writes ctx (B,H,S,D) bf16 + mrow/lrow fp32.
// ---------------------------------------------------------------------------
__global__ __launch_bounds__(256) void k_flash_mfma(
    const ushortT* __restrict__ qkv, ushortT* __restrict__ ctx,
    float* __restrict__ mrow, float* __restrict__ lrow)
{
  __shared__ __align__(16) ushortT Qs[64][LDW];
  __shared__ __align__(16) ushortT Ks[64][LDW];
  __shared__ __align__(16) ushortT Vt[64][LDW];   // [d][k'] permuted
  __shared__ __align__(16) ushortT Ps[64][LDW];   // [q][k'] permuted
  const int tid = threadIdx.x;
  const int lane = tid & 63, w = tid >> 6;
  const int li = lane & 15, gi = lane >> 4;
  const int s0 = blockIdx.x * 64;
  const int bh = blockIdx.z * Hc + blockIdx.y;
  const ushortT* Q = qkv;
  const ushortT* K = qkv + (size_t)XN;
  const ushortT* V = qkv + (size_t)2 * XN;
  const size_t bhb = (size_t)bh * Sc * Dc;

#pragma unroll
  for (int i = 0; i < 2; ++i) {
    int c = tid + i * 256;
    int row = c >> 3, col = (c & 7) * 8;
    *reinterpret_cast<uint4*>(&Qs[row][col]) =
        *reinterpret_cast<const uint4*>(Q + bhb + (size_t)(s0 + row) * 64 + col);
  }

  f32x4 oa[4] = {};
  float m_r[4], l_r[4];
#pragma unroll
  for (int r = 0; r < 4; ++r) { m_r[r] = -1e30f; l_r[r] = 0.f; }

  // V staging map: pair id vp in [0,32), d-chunk vd0; pair rows (ka, ka+16)
  const int vp = tid & 31;
  const int vd0 = (tid >> 5) * 8;
  const int ka = (vp & 15) + (vp >> 4) * 32;
  const int kpb = 8 * (vp & 15) + 4 * (vp >> 4);  // byte offset of k'-pair in Vt row

  for (int kt = 0; kt < 16; ++kt) {
    const int k0 = kt * 64;
    uint4 kreg[2];
#pragma unroll
    for (int i = 0; i < 2; ++i) {
      int c = tid + i * 256;
      int row = c >> 3, col = (c & 7) * 8;
      kreg[i] = *reinterpret_cast<const uint4*>(K + bhb + (size_t)(k0 + row) * 64 + col);
    }
    uint4 va = *reinterpret_cast<const uint4*>(V + bhb + (size_t)(k0 + ka) * 64 + vd0);
    uint4 vb = *reinterpret_cast<const uint4*>(V + bhb + (size_t)(k0 + ka + 16) * 64 + vd0);
    __syncthreads();   // prior tile's LDS reads complete
#pragma unroll
    for (int i = 0; i < 2; ++i) {
      int c = tid + i * 256;
      int row = c >> 3, col = (c & 7) * 8;
      *reinterpret_cast<uint4*>(&Ks[row][col]) = kreg[i];
    }
    const ushortT* pa_ = reinterpret_cast<const ushortT*>(&va);
    const ushortT* pb_ = reinterpret_cast<const ushortT*>(&vb);
#pragma unroll
    for (int i = 0; i < 8; ++i) {
      unsigned int u = (unsigned int)pa_[i] | ((unsigned int)pb_[i] << 16);
      *reinterpret_cast<unsigned int*>(
          reinterpret_cast<char*>(&Vt[vd0 + i][0]) + kpb) = u;
    }
    __syncthreads();   // staged

    // QK^T
    f32x4 sc[4] = {};
#pragma unroll
    for (int ds = 0; ds < 2; ++ds) {
      bf16x8 aq = *reinterpret_cast<const bf16x8*>(&Qs[w * 16 + li][ds * 32 + gi * 8]);
#pragma unroll
      for (int nf = 0; nf < 4; ++nf) {
        bf16x8 bk = *reinterpret_cast<const bf16x8*>(&Ks[nf * 16 + li][ds * 32 + gi * 8]);
        sc[nf] = MFMA_BF16(aq, bk, sc[nf], 0, 0, 0);
      }
    }

    // online softmax (wave-local; rows r live in acc component r)
    float esc[4];
#pragma unroll
    for (int r = 0; r < 4; ++r) {
      float v = fmaxf(fmaxf(sc[0][r], sc[1][r]), fmaxf(sc[2][r], sc[3][r]));
      v = fmaxf(v, __shfl_xor(v, 1));
      v = fmaxf(v, __shfl_xor(v, 2));
      v = fmaxf(v, __shfl_xor(v, 4));
      v = fmaxf(v, __shfl_xor(v, 8));
      float mnew = fmaxf(m_r[r], v);
      esc[r] = __expf(m_r[r] - mnew);
      m_r[r] = mnew;
    }
    float p[4][4];
#pragma unroll
    for (int r = 0; r < 4; ++r) {
      float s = 0.f;
#pragma unroll
      for (int nf = 0; nf < 4; ++nf) { p[nf][r] = __expf(sc[nf][r] - m_r[r]); s += p[nf][r]; }
      s += __shfl_xor(s, 1); s += __shfl_xor(s, 2);
      s += __shfl_xor(s, 4); s += __shfl_xor(s, 8);
      l_r[r] = l_r[r] * esc[r] + s;
#pragma unroll
      for (int nf = 0; nf < 4; ++nf) oa[nf][r] *= esc[r];
    }
    // pack P (bf16) into Ps rows (wave-private): cols k' = 4*li + nf
#pragma unroll
    for (int r = 0; r < 4; ++r) {
      unsigned int u0 = (unsigned int)f2bf(p[0][r]) | ((unsigned int)f2bf(p[1][r]) << 16);
      unsigned int u1 = (unsigned int)f2bf(p[2][r]) | ((unsigned int)f2bf(p[3][r]) << 16);
      uint2 uu; uu.x = u0; uu.y = u1;
      *reinterpret_cast<uint2*>(
          reinterpret_cast<char*>(&Ps[w * 16 + gi * 4 + r][0]) + li * 8) = uu;
    }
    // PV (contraction over permuted k'; P and Vt use the same permutation)
#pragma unroll
    for (int ks = 0; ks < 2; ++ks) {
      bf16x8 pa = *reinterpret_cast<const bf16x8*>(&Ps[w * 16 + li][ks * 32 + gi * 8]);
#pragma unroll
      for (int nf = 0; nf < 4; ++nf) {
        bf16x8 vv = *reinterpret_cast<const bf16x8*>(&Vt[nf * 16 + li][ks * 32 + gi * 8]);
        oa[nf] = MFMA_BF16(pa, vv, oa[nf], 0, 0, 0);
      }
    }
  }

  float inv[4];
#pragma unroll
  for (int r = 0; r < 4; ++r) inv[r] = 1.0f / l_r[r];
#pragma unroll
  for (int nf = 0; nf < 4; ++nf)
#pragma unroll
    for (int r = 0; r < 4; ++r) {
      int q = s0 + w * 16 + gi * 4 + r;
      ctx[bhb + (size_t)q * 64 + nf * 16 + li] = f2bf(oa[nf][r] * inv[r]);
    }
  if (li == 0) {
#pragma unroll
    for (int r = 0; r < 4; ++r) {
      int q = s0 + w * 16 + gi * 4 + r;
      mrow[(size_t)bh * Sc + q] = m_r[r];
      lrow[(size_t)bh * Sc + q] = l_r[r];
    }
  }
}

// ---------------------------------------------------------------------------
// K3: out projection, bf16 MFMA. A = ctx gathered (B,H,S,D)->(m=(b,s), e=(h,d));
// W=(E,E). M=4096, N=1024, K=1024. Same 128x128 structure. fp32 output + bias.
// ---------------------------------------------------------------------------
__global__ __launch_bounds__(256) void k_outproj_mfma(
    const ushortT* __restrict__ ctx, const ushortT* __restrict__ wo,
    const float* __restrict__ bias, float* __restrict__ out)
{
  __shared__ __align__(16) ushortT As[128][LDW];
  __shared__ __align__(16) ushortT Bs[128][LDW];
  const int tid = threadIdx.x;
  const int lane = tid & 63, wid = tid >> 6;
  const int wm = wid >> 1, wn = wid & 1;
  const int li = lane & 15, gi = lane >> 4;
  const int m0 = blockIdx.x * 128, n0 = blockIdx.y * 128;

  f32x4 acc[4][4] = {};

  for (int k0 = 0; k0 < 1024; k0 += 64) {
    const int h = k0 >> 6;          // BK==Dc: one head per K-step
    __syncthreads();
#pragma unroll
    for (int i = 0; i < 4; ++i) {
      int c = tid + i * 256;
      int row = c >> 3, col = (c & 7) * 8;    // col < 64 == within head
      int m = m0 + row;
      int b_ = m >> 10, s = m & 1023;
      *reinterpret_cast<uint4*>(&As[row][col]) =
          *reinterpret_cast<const uint4*>(
              ctx + (((size_t)b_ * Hc + h) * Sc + s) * Dc + col);
      *reinterpret_cast<uint4*>(&Bs[row][col]) =
          *reinterpret_cast<const uint4*>(wo + (size_t)(n0 + row) * 1024 + k0 + col);
    }
    __syncthreads();
#pragma unroll
    for (int ks = 0; ks < 2; ++ks) {
      bf16x8 a[4], b[4];
#pragma unroll
      for (int t = 0; t < 4; ++t) {
        a[t] = *reinterpret_cast<const bf16x8*>(&As[wm * 64 + t * 16 + li][ks * 32 + gi * 8]);
        b[t] = *reinterpret_cast<const bf16x8*>(&Bs[wn * 64 + t * 16 + li][ks * 32 + gi * 8]);
      }
#pragma unroll
      for (int mi = 0; mi < 4; ++mi)
#pragma unroll
        for (int ni = 0; ni < 4; ++ni)
          acc[mi][ni] = MFMA_BF16(a[mi], b[ni], acc[mi][ni], 0, 0, 0);
    }
  }

#pragma unroll
  for (int ni = 0; ni < 4; ++ni) {
    int n = n0 + wn * 64 + ni * 16 + li;
    float bv = bias[n];
#pragma unroll
    for (int mi = 0; mi < 4; ++mi)
#pragma unroll
      for (int r = 0; r < 4; ++r) {
        int m = m0 + wm * 64 + mi * 16 + gi * 4 + r;
        out[(size_t)m * 1024 + n] = acc[mi][ni][r] + bv;
      }
  }
}

// ---------------------------------------------------------------------------
// K4: head-averaged attention weights * gate (unnormalized), bf16 MFMA.
// Block = (64 k-cols, 64 q-rows, b); head loop inside; scores recomputed
// bitwise-identically to k_flash; w = exp(s - m)/l with m,l from k_flash.
// ---------------------------------------------------------------------------
__global__ __launch_bounds__(256) void k_avggate_mfma(
    const ushortT* __restrict__ qkv, const float* __restrict__ mrow,
    const float* __restrict__ lrow, const float* __restrict__ gate,
    float* __restrict__ out1)
{
  __shared__ __align__(16) ushortT Qs[64][LDW];
  __shared__ __align__(16) ushortT Ks[64][LDW];
  const int tid = threadIdx.x;
  const int lane = tid & 63, w = tid >> 6;
  const int li = lane & 15, gi = lane >> 4;
  const int c0 = blockIdx.x * 64;
  const int s0 = blockIdx.y * 64;
  const int b = blockIdx.z;
  const ushortT* Q = qkv;
  const ushortT* K = qkv + (size_t)XN;

  f32x4 avg[4] = {};

  for (int h = 0; h < Hc; ++h) {
    const size_t bh = (size_t)b * Hc + h;
    const size_t bhb = bh * Sc * Dc;
    float mh[4], liv[4];
#pragma unroll
    for (int r = 0; r < 4; ++r) {
      int q = s0 + w * 16 + gi * 4 + r;
      mh[r] = mrow[bh * Sc + q];
      liv[r] = 0.0625f / lrow[bh * Sc + q];   // 1/H folded in
    }
    uint4 qreg[2], kreg[2];
#pragma unroll
    for (int i = 0; i < 2; ++i) {
      int c = tid + i * 256;
      int row = c >> 3, col = (c & 7) * 8;
      qreg[i] = *reinterpret_cast<const uint4*>(Q + bhb + (size_t)(s0 + row) * 64 + col);
      kreg[i] = *reinterpret_cast<const uint4*>(K + bhb + (size_t)(c0 + row) * 64 + col);
    }
    __syncthreads();
#pragma unroll
    for (int i = 0; i < 2; ++i) {
      int c = tid + i * 256;
      int row = c >> 3, col = (c & 7) * 8;
      *reinterpret_cast<uint4*>(&Qs[row][col]) = qreg[i];
      *reinterpret_cast<uint4*>(&Ks[row][col]) = kreg[i];
    }
    __syncthreads();

    f32x4 sc[4] = {};
#pragma unroll
    for (int ds = 0; ds < 2; ++ds) {
      bf16x8 aq = *reinterpret_cast<const bf16x8*>(&Qs[w * 16 + li][ds * 32 + gi * 8]);
#pragma unroll
      for (int nf = 0; nf < 4; ++nf) {
        bf16x8 bk = *reinterpret_cast<const bf16x8*>(&Ks[nf * 16 + li][ds * 32 + gi * 8]);
        sc[nf] = MFMA_BF16(aq, bk, sc[nf], 0, 0, 0);
      }
    }
#pragma unroll
    for (int nf = 0; nf < 4; ++nf)
#pragma unroll
      for (int r = 0; r < 4; ++r)
        avg[nf][r] += __expf(sc[nf][r] - mh[r]) * liv[r];
  }

#pragma unroll
  for (int nf = 0; nf < 4; ++nf)
#pragma unroll
    for (int r = 0; r < 4; ++r) {
      int q = s0 + w * 16 + gi * 4 + r;
      size_t o = ((size_t)b * Sc + q) * Sc + c0 + nf * 16 + li;
      out1[o] = avg[nf][r] * gate[o];
    }
}

// ---------------------------------------------------------------------------
// K5: in-place row renormalization: x / (sum(x) + 1e-12)
// ---------------------------------------------------------------------------
__global__ __launch_bounds__(256) void k_renorm(float* __restrict__ out1)
{
  __shared__ float wsum[4];
  const int tid = threadIdx.x;
  float* row = out1 + (size_t)blockIdx.x * Sc;
  float4 v = *reinterpret_cast<const float4*>(row + tid * 4);
  float s = v.x + v.y + v.z + v.w;
#pragma unroll
  for (int off = 1; off < 64; off <<= 1) s += __shfl_xor(s, off);
  if ((tid & 63) == 0) wsum[tid >> 6] = s;
  __syncthreads();
  float inv = 1.0f / (wsum[0] + wsum[1] + wsum[2] + wsum[3] + 1e-12f);
  v.x *= inv; v.y *= inv; v.z *= inv; v.w *= inv;
  *reinterpret_cast<float4*>(row + tid * 4) = v;
}

// ---------------------------------------------------------------------------
extern "C" void kernel_launch(void* const* d_in, const int* in_sizes, int n_in,
                              void* d_out, int out_size, void* d_ws, size_t ws_size,
                              hipStream_t stream) {
  const float* query = (const float*)d_in[0];
  const float* key   = (const float*)d_in[1];
  const float* value = (const float*)d_in[2];
  const float* gate  = (const float*)d_in[3];
  const float* w_in  = (const float*)d_in[4];
  const float* b_in  = (const float*)d_in[5];
  const float* w_out = (const float*)d_in[6];
  const float* b_out = (const float*)d_in[7];

  float* out0 = (float*)d_out;                       // attn_output (B,S,E)
  float* out1 = out0 + (size_t)Bc * Sc * Ec;         // gated (B,S,S)

  // bf16 workspace layout (ushort elements)
  ushortT* xq   = (ushortT*)d_ws;                    // 4M
  ushortT* xk   = xq + (size_t)XN;                   // 4M
  ushortT* xv   = xk + (size_t)XN;                   // 4M
  ushortT* wi   = xv + (size_t)XN;                   // 3M
  ushortT* wo   = wi + (size_t)3 * Ec * Ec;          // 1M
  ushortT* qkvb = wo + (size_t)Ec * Ec;              // 12M (3,B,H,S,D)
  ushortT* ctxb = xq;                                // alias: xq dead after k_qkv
  float* mrow = (float*)(qkvb + (size_t)3 * XN);     // 64K
  float* lrow = mrow + (size_t)Bc * Hc * Sc;         // 64K

  hipLaunchKernelGGL(k_cast, dim3(2048, 5), dim3(256), 0, stream,
                     query, key, value, w_in, w_out, xq, xk, xv, wi, wo);
  hipLaunchKernelGGL(k_qkv_mfma, dim3(32, 24), dim3(256), 0, stream,
                     xq, xk, xv, wi, b_in, qkvb);
  hipLaunchKernelGGL(k_flash_mfma, dim3(16, 16, 4), dim3(256), 0, stream,
                     qkvb, ctxb, mrow, lrow);
  hipLaunchKernelGGL(k_outproj_mfma, dim3(32, 8), dim3(256), 0, stream,
                     ctxb, wo, b_out, out0);
  hipLaunchKernelGGL(k_avggate_mfma, dim3(16, 16, 4), dim3(256), 0, stream,
                     qkvb, mrow, lrow, gate, out1);
  hipLaunchKernelGGL(k_renorm, dim3(Bc * Sc), dim3(256), 0, stream, out1);
}

// Round 6
// 347.105 us; speedup vs baseline: 5.1504x; 1.0031x over previous
//
#include <hip/hip_runtime.h>

typedef unsigned short ushortT;
typedef __attribute__((ext_vector_type(8))) short bf16x8;
typedef __attribute__((ext_vector_type(4))) float f32x4;

constexpr int Ec = 1024;   // embed
constexpr int Hc = 16;     // heads
constexpr int Dc = 64;     // head dim
constexpr int Bc = 4;      // batch
constexpr int Sc = 1024;   // seq
constexpr int XN = Bc * Sc * Ec;          // 4194304 (elements of one B,S,E tensor)
constexpr int LDW = 72;    // LDS row stride in bf16 (144B: 16B-aligned, good bank spread)

#define MFMA_BF16 __builtin_amdgcn_mfma_f32_16x16x32_bf16

__device__ __forceinline__ ushortT f2bf(float f) {
  union { float f; unsigned int u; } x{f};
  unsigned int r = x.u + 0x7fffu + ((x.u >> 16) & 1u);   // RNE
  return (ushortT)(r >> 16);
}

// ---------------------------------------------------------------------------
// K0: cast fp32 inputs/weights -> bf16 workspace copies.
// seg: 0=query 1=key 2=value 3=in_proj_w 4=out_proj_w
// ---------------------------------------------------------------------------
struct US8 { ushortT u[8]; };

__global__ __launch_bounds__(256) void k_cast(
    const float* __restrict__ q, const float* __restrict__ k,
    const float* __restrict__ v, const float* __restrict__ wi,
    const float* __restrict__ wo,
    ushortT* __restrict__ oq, ushortT* __restrict__ ok,
    ushortT* __restrict__ ov, ushortT* __restrict__ owi,
    ushortT* __restrict__ owo)
{
  const int seg = blockIdx.y;
  const float* src; ushortT* dst; int n;
  if      (seg == 0) { src = q;  dst = oq;  n = XN; }
  else if (seg == 1) { src = k;  dst = ok;  n = XN; }
  else if (seg == 2) { src = v;  dst = ov;  n = XN; }
  else if (seg == 3) { src = wi; dst = owi; n = 3 * Ec * Ec; }
  else               { src = wo; dst = owo; n = Ec * Ec; }
  int base = (blockIdx.x * 256 + threadIdx.x) * 8;
  if (base >= n) return;
  float4 a = *reinterpret_cast<const float4*>(src + base);
  float4 b = *reinterpret_cast<const float4*>(src + base + 4);
  US8 o;
  o.u[0] = f2bf(a.x); o.u[1] = f2bf(a.y); o.u[2] = f2bf(a.z); o.u[3] = f2bf(a.w);
  o.u[4] = f2bf(b.x); o.u[5] = f2bf(b.y); o.u[6] = f2bf(b.z); o.u[7] = f2bf(b.w);
  *reinterpret_cast<US8*>(dst + base) = o;
}

// ---------------------------------------------------------------------------
// K1: QKV projection, bf16 MFMA. C[m,n] = X[m,:] . W[n,:] + bias[n]
// M=4096 (B*S), N=3072 (3E), K=1024. Block 128x128, BK=64, 4 waves (2x2),
// each wave 64x64 = 4x4 fragments of 16x16x32.
// Output (3,B,H,S,D) bf16, q scaled by 1/8.
// ---------------------------------------------------------------------------
__global__ __launch_bounds__(256) void k_qkv_mfma(
    const ushortT* __restrict__ xq, const ushortT* __restrict__ xk,
    const ushortT* __restrict__ xv, const ushortT* __restrict__ wi,
    const float* __restrict__ bias, ushortT* __restrict__ qkv)
{
  __shared__ __align__(16) ushortT As[128][LDW];
  __shared__ __align__(16) ushortT Bs[128][LDW];
  const int tid = threadIdx.x;
  const int lane = tid & 63, wid = tid >> 6;
  const int wm = wid >> 1, wn = wid & 1;
  const int li = lane & 15, gi = lane >> 4;
  const int m0 = blockIdx.x * 128, n0 = blockIdx.y * 128;
  const int third = n0 >> 10;
  const ushortT* x = (third == 0) ? xq : (third == 1) ? xk : xv;

  f32x4 acc[4][4] = {};

  for (int k0 = 0; k0 < 1024; k0 += 64) {
    __syncthreads();
#pragma unroll
    for (int i = 0; i < 4; ++i) {
      int c = tid + i * 256;                 // 0..1023
      int row = c >> 3, col = (c & 7) * 8;
      *reinterpret_cast<uint4*>(&As[row][col]) =
          *reinterpret_cast<const uint4*>(x + (size_t)(m0 + row) * 1024 + k0 + col);
      *reinterpret_cast<uint4*>(&Bs[row][col]) =
          *reinterpret_cast<const uint4*>(wi + (size_t)(n0 + row) * 1024 + k0 + col);
    }
    __syncthreads();
#pragma unroll
    for (int ks = 0; ks < 2; ++ks) {
      bf16x8 a[4], b[4];
#pragma unroll
      for (int t = 0; t < 4; ++t) {
        a[t] = *reinterpret_cast<const bf16x8*>(&As[wm * 64 + t * 16 + li][ks * 32 + gi * 8]);
        b[t] = *reinterpret_cast<const bf16x8*>(&Bs[wn * 64 + t * 16 + li][ks * 32 + gi * 8]);
      }
#pragma unroll
      for (int mi = 0; mi < 4; ++mi)
#pragma unroll
        for (int ni = 0; ni < 4; ++ni)
          acc[mi][ni] = MFMA_BF16(a[mi], b[ni], acc[mi][ni], 0, 0, 0);
    }
  }

  const float scale = (third == 0) ? 0.125f : 1.0f;
#pragma unroll
  for (int ni = 0; ni < 4; ++ni) {
    int n = n0 + wn * 64 + ni * 16 + li;
    float bv = bias[n];
    int h = (n >> 6) & 15, d = n & 63;
#pragma unroll
    for (int mi = 0; mi < 4; ++mi)
#pragma unroll
      for (int r = 0; r < 4; ++r) {
        int m = m0 + wm * 64 + mi * 16 + gi * 4 + r;
        int b_ = m >> 10, s = m & 1023;
        size_t o = ((((size_t)third * Bc + b_) * Hc + h) * Sc + s) * Dc + d;
        qkv[o] = f2bf((acc[mi][ni][r] + bv) * scale);
      }
  }
}

// ---------------------------------------------------------------------------
// K2: flash attention, bf16 MFMA. Block = (qtile 64, h, b), 4 waves; wave w
// owns q rows [16w,16w+16). Scores C[q][k]: wave-local softmax via shfl.
// P and V use a per-tile k-permutation k' = 4*(k&15)+(k>>4) consistently.
// Writes ctx (B,H,S,D) bf16 + mrow/lrow fp32.
// ---------------------------------------------------------------------------
__global__ __launch_bounds__(256) void k_flash_mfma(
    const ushortT* __restrict__ qkv, ushortT* __restrict__ ctx,
    float* __restrict__ mrow, float* __restrict__ lrow)
{
  __shared__ __align__(16) ushortT Qs[64][LDW];
  __shared__ __align__(16) ushortT Ks[64][LDW];
  __shared__ __align__(16) ushortT Vt[64][LDW];   // [d][k'] permuted
  __shared__ __align__(16) ushortT Ps[64][LDW];   // [q][k'] permuted
  const int tid = threadIdx.x;
  const int lane = tid & 63, w = tid >> 6;
  const int li = lane & 15, gi = lane >> 4;
  const int s0 = blockIdx.x * 64;
  const int bh = blockIdx.z * Hc + blockIdx.y;
  const ushortT* Q = qkv;
  const ushortT* K = qkv + (size_t)XN;
  const ushortT* V = qkv + (size_t)2 * XN;
  const size_t bhb = (size_t)bh * Sc * Dc;

#pragma unroll
  for (int i = 0; i < 2; ++i) {
    int c = tid + i * 256;
    int row = c >> 3, col = (c & 7) * 8;
    *reinterpret_cast<uint4*>(&Qs[row][col]) =
        *reinterpret_cast<const uint4*>(Q + bhb + (size_t)(s0 + row) * 64 + col);
  }

  f32x4 oa[4] = {};
  float m_r[4], l_r[4];
#pragma unroll
  for (int r = 0; r < 4; ++r) { m_r[r] = -1e30f; l_r[r] = 0.f; }

  // V staging map: pair id vp in [0,32), d-chunk vd0; pair rows (ka, ka+16)
  const int vp = tid & 31;
  const int vd0 = (tid >> 5) * 8;
  const int ka = (vp & 15) + (vp >> 4) * 32;
  const int kpb = 8 * (vp & 15) + 4 * (vp >> 4);  // byte offset of k'-pair in Vt row

  for (int kt = 0; kt < 16; ++kt) {
    const int k0 = kt * 64;
    uint4 kreg[2];
#pragma unroll
    for (int i = 0; i < 2; ++i) {
      int c = tid + i * 256;
      int row = c >> 3, col = (c & 7) * 8;
      kreg[i] = *reinterpret_cast<const uint4*>(K + bhb + (size_t)(k0 + row) * 64 + col);
    }
    uint4 va = *reinterpret_cast<const uint4*>(V + bhb + (size_t)(k0 + ka) * 64 + vd0);
    uint4 vb = *reinterpret_cast<const uint4*>(V + bhb + (size_t)(k0 + ka + 16) * 64 + vd0);
    __syncthreads();   // prior tile's LDS reads complete
#pragma unroll
    for (int i = 0; i < 2; ++i) {
      int c = tid + i * 256;
      int row = c >> 3, col = (c & 7) * 8;
      *reinterpret_cast<uint4*>(&Ks[row][col]) = kreg[i];
    }
    const ushortT* pa_ = reinterpret_cast<const ushortT*>(&va);
    const ushortT* pb_ = reinterpret_cast<const ushortT*>(&vb);
#pragma unroll
    for (int i = 0; i < 8; ++i) {
      unsigned int u = (unsigned int)pa_[i] | ((unsigned int)pb_[i] << 16);
      *reinterpret_cast<unsigned int*>(
          reinterpret_cast<char*>(&Vt[vd0 + i][0]) + kpb) = u;
    }
    __syncthreads();   // staged

    // QK^T
    f32x4 sc[4] = {};
#pragma unroll
    for (int ds = 0; ds < 2; ++ds) {
      bf16x8 aq = *reinterpret_cast<const bf16x8*>(&Qs[w * 16 + li][ds * 32 + gi * 8]);
#pragma unroll
      for (int nf = 0; nf < 4; ++nf) {
        bf16x8 bk = *reinterpret_cast<const bf16x8*>(&Ks[nf * 16 + li][ds * 32 + gi * 8]);
        sc[nf] = MFMA_BF16(aq, bk, sc[nf], 0, 0, 0);
      }
    }

    // online softmax (wave-local; rows r live in acc component r)
    float esc[4];
#pragma unroll
    for (int r = 0; r < 4; ++r) {
      float v = fmaxf(fmaxf(sc[0][r], sc[1][r]), fmaxf(sc[2][r], sc[3][r]));
      v = fmaxf(v, __shfl_xor(v, 1));
      v = fmaxf(v, __shfl_xor(v, 2));
      v = fmaxf(v, __shfl_xor(v, 4));
      v = fmaxf(v, __shfl_xor(v, 8));
      float mnew = fmaxf(m_r[r], v);
      esc[r] = __expf(m_r[r] - mnew);
      m_r[r] = mnew;
    }
    float p[4][4];
#pragma unroll
    for (int r = 0; r < 4; ++r) {
      float s = 0.f;
#pragma unroll
      for (int nf = 0; nf < 4; ++nf) { p[nf][r] = __expf(sc[nf][r] - m_r[r]); s += p[nf][r]; }
      s += __shfl_xor(s, 1); s += __shfl_xor(s, 2);
      s += __shfl_xor(s, 4); s += __shfl_xor(s, 8);
      l_r[r] = l_r[r] * esc[r] + s;
#pragma unroll
      for (int nf = 0; nf < 4; ++nf) oa[nf][r] *= esc[r];
    }
    // pack P (bf16) into Ps rows (wave-private): cols k' = 4*li + nf
#pragma unroll
    for (int r = 0; r < 4; ++r) {
      unsigned int u0 = (unsigned int)f2bf(p[0][r]) | ((unsigned int)f2bf(p[1][r]) << 16);
      unsigned int u1 = (unsigned int)f2bf(p[2][r]) | ((unsigned int)f2bf(p[3][r]) << 16);
      uint2 uu; uu.x = u0; uu.y = u1;
      *reinterpret_cast<uint2*>(
          reinterpret_cast<char*>(&Ps[w * 16 + gi * 4 + r][0]) + li * 8) = uu;
    }
    // PV (contraction over permuted k'; P and Vt use the same permutation)
#pragma unroll
    for (int ks = 0; ks < 2; ++ks) {
      bf16x8 pa = *reinterpret_cast<const bf16x8*>(&Ps[w * 16 + li][ks * 32 + gi * 8]);
#pragma unroll
      for (int nf = 0; nf < 4; ++nf) {
        bf16x8 vv = *reinterpret_cast<const bf16x8*>(&Vt[nf * 16 + li][ks * 32 + gi * 8]);
        oa[nf] = MFMA_BF16(pa, vv, oa[nf], 0, 0, 0);
      }
    }
  }

  float inv[4];
#pragma unroll
  for (int r = 0; r < 4; ++r) inv[r] = 1.0f / l_r[r];
#pragma unroll
  for (int nf = 0; nf < 4; ++nf)
#pragma unroll
    for (int r = 0; r < 4; ++r) {
      int q = s0 + w * 16 + gi * 4 + r;
      ctx[bhb + (size_t)q * 64 + nf * 16 + li] = f2bf(oa[nf][r] * inv[r]);
    }
  if (li == 0) {
#pragma unroll
    for (int r = 0; r < 4; ++r) {
      int q = s0 + w * 16 + gi * 4 + r;
      mrow[(size_t)bh * Sc + q] = m_r[r];
      lrow[(size_t)bh * Sc + q] = l_r[r];
    }
  }
}

// ---------------------------------------------------------------------------
// K3: out projection, bf16 MFMA. A = ctx gathered (B,H,S,D)->(m=(b,s), e=(h,d));
// W=(E,E). M=4096, N=1024, K=1024. Same 128x128 structure. fp32 output + bias.
// ---------------------------------------------------------------------------
__global__ __launch_bounds__(256) void k_outproj_mfma(
    const ushortT* __restrict__ ctx, const ushortT* __restrict__ wo,
    const float* __restrict__ bias, float* __restrict__ out)
{
  __shared__ __align__(16) ushortT As[128][LDW];
  __shared__ __align__(16) ushortT Bs[128][LDW];
  const int tid = threadIdx.x;
  const int lane = tid & 63, wid = tid >> 6;
  const int wm = wid >> 1, wn = wid & 1;
  const int li = lane & 15, gi = lane >> 4;
  const int m0 = blockIdx.x * 128, n0 = blockIdx.y * 128;

  f32x4 acc[4][4] = {};

  for (int k0 = 0; k0 < 1024; k0 += 64) {
    const int h = k0 >> 6;          // BK==Dc: one head per K-step
    __syncthreads();
#pragma unroll
    for (int i = 0; i < 4; ++i) {
      int c = tid + i * 256;
      int row = c >> 3, col = (c & 7) * 8;    // col < 64 == within head
      int m = m0 + row;
      int b_ = m >> 10, s = m & 1023;
      *reinterpret_cast<uint4*>(&As[row][col]) =
          *reinterpret_cast<const uint4*>(
              ctx + (((size_t)b_ * Hc + h) * Sc + s) * Dc + col);
      *reinterpret_cast<uint4*>(&Bs[row][col]) =
          *reinterpret_cast<const uint4*>(wo + (size_t)(n0 + row) * 1024 + k0 + col);
    }
    __syncthreads();
#pragma unroll
    for (int ks = 0; ks < 2; ++ks) {
      bf16x8 a[4], b[4];
#pragma unroll
      for (int t = 0; t < 4; ++t) {
        a[t] = *reinterpret_cast<const bf16x8*>(&As[wm * 64 + t * 16 + li][ks * 32 + gi * 8]);
        b[t] = *reinterpret_cast<const bf16x8*>(&Bs[wn * 64 + t * 16 + li][ks * 32 + gi * 8]);
      }
#pragma unroll
      for (int mi = 0; mi < 4; ++mi)
#pragma unroll
        for (int ni = 0; ni < 4; ++ni)
          acc[mi][ni] = MFMA_BF16(a[mi], b[ni], acc[mi][ni], 0, 0, 0);
    }
  }

#pragma unroll
  for (int ni = 0; ni < 4; ++ni) {
    int n = n0 + wn * 64 + ni * 16 + li;
    float bv = bias[n];
#pragma unroll
    for (int mi = 0; mi < 4; ++mi)
#pragma unroll
      for (int r = 0; r < 4; ++r) {
        int m = m0 + wm * 64 + mi * 16 + gi * 4 + r;
        out[(size_t)m * 1024 + n] = acc[mi][ni][r] + bv;
      }
  }
}

// ---------------------------------------------------------------------------
// K4: head-averaged attention weights * gate (unnormalized), bf16 MFMA.
// NO LDS, NO barriers: A/B fragments are row-slices -> direct global
// dwordx4 loads per lane (L1 dedupes the 4x wave redundancy on K; Q/K tiles
// are L2-resident across blocks). Scores recomputed in the SAME MFMA
// accumulation order as k_flash (ds outer, nf inner) for m/l consistency.
// ---------------------------------------------------------------------------
__global__ __launch_bounds__(256) void k_avggate_mfma(
    const ushortT* __restrict__ qkv, const float* __restrict__ mrow,
    const float* __restrict__ lrow, const float* __restrict__ gate,
    float* __restrict__ out1)
{
  const int tid = threadIdx.x;
  const int lane = tid & 63, w = tid >> 6;
  const int li = lane & 15, gi = lane >> 4;
  const int c0 = blockIdx.x * 64;
  const int s0 = blockIdx.y * 64;
  const int b = blockIdx.z;
  const ushortT* Q = qkv;
  const ushortT* K = qkv + (size_t)XN;

  const int qrow = s0 + w * 16 + li;          // A-frag row (per lane)
  f32x4 avg[4] = {};

  for (int h = 0; h < Hc; ++h) {
    const size_t bh = (size_t)b * Hc + h;
    const size_t bhb = bh * Sc * Dc;
    float mh[4], liv[4];
#pragma unroll
    for (int r = 0; r < 4; ++r) {
      int q = s0 + w * 16 + gi * 4 + r;
      mh[r] = mrow[bh * Sc + q];
      liv[r] = 0.0625f / lrow[bh * Sc + q];   // 1/H folded in
    }
    const ushortT* Qb = Q + bhb;
    const ushortT* Kb = K + bhb;

    f32x4 sc[4] = {};
#pragma unroll
    for (int ds = 0; ds < 2; ++ds) {
      bf16x8 aq = *reinterpret_cast<const bf16x8*>(
          Qb + (size_t)qrow * 64 + ds * 32 + gi * 8);
#pragma unroll
      for (int nf = 0; nf < 4; ++nf) {
        bf16x8 bk = *reinterpret_cast<const bf16x8*>(
            Kb + (size_t)(c0 + nf * 16 + li) * 64 + ds * 32 + gi * 8);
        sc[nf] = MFMA_BF16(aq, bk, sc[nf], 0, 0, 0);
      }
    }
#pragma unroll
    for (int nf = 0; nf < 4; ++nf)
#pragma unroll
      for (int r = 0; r < 4; ++r)
        avg[nf][r] += __expf(sc[nf][r] - mh[r]) * liv[r];
  }

#pragma unroll
  for (int nf = 0; nf < 4; ++nf)
#pragma unroll
    for (int r = 0; r < 4; ++r) {
      int q = s0 + w * 16 + gi * 4 + r;
      size_t o = ((size_t)b * Sc + q) * Sc + c0 + nf * 16 + li;
      out1[o] = avg[nf][r] * gate[o];
    }
}

// ---------------------------------------------------------------------------
// K5: in-place row renormalization: x / (sum(x) + 1e-12)
// ---------------------------------------------------------------------------
__global__ __launch_bounds__(256) void k_renorm(float* __restrict__ out1)
{
  __shared__ float wsum[4];
  const int tid = threadIdx.x;
  float* row = out1 + (size_t)blockIdx.x * Sc;
  float4 v = *reinterpret_cast<const float4*>(row + tid * 4);
  float s = v.x + v.y + v.z + v.w;
#pragma unroll
  for (int off = 1; off < 64; off <<= 1) s += __shfl_xor(s, off);
  if ((tid & 63) == 0) wsum[tid >> 6] = s;
  __syncthreads();
  float inv = 1.0f / (wsum[0] + wsum[1] + wsum[2] + wsum[3] + 1e-12f);
  v.x *= inv; v.y *= inv; v.z *= inv; v.w *= inv;
  *reinterpret_cast<float4*>(row + tid * 4) = v;
}

// ---------------------------------------------------------------------------
extern "C" void kernel_launch(void* const* d_in, const int* in_sizes, int n_in,
                              void* d_out, int out_size, void* d_ws, size_t ws_size,
                              hipStream_t stream) {
  const float* query = (const float*)d_in[0];
  const float* key   = (const float*)d_in[1];
  const float* value = (const float*)d_in[2];
  const float* gate  = (const float*)d_in[3];
  const float* w_in  = (const float*)d_in[4];
  const float* b_in  = (const float*)d_in[5];
  const float* w_out = (const float*)d_in[6];
  const float* b_out = (const float*)d_in[7];

  float* out0 = (float*)d_out;                       // attn_output (B,S,E)
  float* out1 = out0 + (size_t)Bc * Sc * Ec;         // gated (B,S,S)

  // bf16 workspace layout (ushort elements)
  ushortT* xq   = (ushortT*)d_ws;                    // 4M
  ushortT* xk   = xq + (size_t)XN;                   // 4M
  ushortT* xv   = xk + (size_t)XN;                   // 4M
  ushortT* wi   = xv + (size_t)XN;                   // 3M
  ushortT* wo   = wi + (size_t)3 * Ec * Ec;          // 1M
  ushortT* qkvb = wo + (size_t)Ec * Ec;              // 12M (3,B,H,S,D)
  ushortT* ctxb = xq;                                // alias: xq dead after k_qkv
  float* mrow = (float*)(qkvb + (size_t)3 * XN);     // 64K
  float* lrow = mrow + (size_t)Bc * Hc * Sc;         // 64K

  hipLaunchKernelGGL(k_cast, dim3(2048, 5), dim3(256), 0, stream,
                     query, key, value, w_in, w_out, xq, xk, xv, wi, wo);
  hipLaunchKernelGGL(k_qkv_mfma, dim3(32, 24), dim3(256), 0, stream,
                     xq, xk, xv, wi, b_in, qkvb);
  hipLaunchKernelGGL(k_flash_mfma, dim3(16, 16, 4), dim3(256), 0, stream,
                     qkvb, ctxb, mrow, lrow);
  hipLaunchKernelGGL(k_outproj_mfma, dim3(32, 8), dim3(256), 0, stream,
                     ctxb, wo, b_out, out0);
  hipLaunchKernelGGL(k_avggate_mfma, dim3(16, 16, 4), dim3(256), 0, stream,
                     qkvb, mrow, lrow, gate, out1);
  hipLaunchKernelGGL(k_renorm, dim3(Bc * Sc), dim3(256), 0, stream, out1);
}

// Round 7
// 346.541 us; speedup vs baseline: 5.1588x; 1.0016x over previous
//
#include <hip/hip_runtime.h>

typedef unsigned short ushortT;
typedef __attribute__((ext_vector_type(8))) short bf16x8;
typedef __attribute__((ext_vector_type(4))) float f32x4;

constexpr int Ec = 1024;   // embed
constexpr int Hc = 16;     // heads
constexpr int Dc = 64;     // head dim
constexpr int Bc = 4;      // batch
constexpr int Sc = 1024;   // seq
constexpr int XN = Bc * Sc * Ec;          // 4194304 (elements of one B,S,E tensor)
constexpr int LDW = 72;    // LDS row stride in bf16 (144B: 16B-aligned, good bank spread)

#define MFMA_BF16 __builtin_amdgcn_mfma_f32_16x16x32_bf16

__device__ __forceinline__ ushortT f2bf(float f) {
  union { float f; unsigned int u; } x{f};
  unsigned int r = x.u + 0x7fffu + ((x.u >> 16) & 1u);   // RNE
  return (ushortT)(r >> 16);
}

// ---------------------------------------------------------------------------
// K0: cast fp32 inputs/weights -> bf16 workspace copies.
// ---------------------------------------------------------------------------
struct US8 { ushortT u[8]; };

__global__ __launch_bounds__(256) void k_cast(
    const float* __restrict__ q, const float* __restrict__ k,
    const float* __restrict__ v, const float* __restrict__ wi,
    const float* __restrict__ wo,
    ushortT* __restrict__ oq, ushortT* __restrict__ ok,
    ushortT* __restrict__ ov, ushortT* __restrict__ owi,
    ushortT* __restrict__ owo)
{
  const int seg = blockIdx.y;
  const float* src; ushortT* dst; int n;
  if      (seg == 0) { src = q;  dst = oq;  n = XN; }
  else if (seg == 1) { src = k;  dst = ok;  n = XN; }
  else if (seg == 2) { src = v;  dst = ov;  n = XN; }
  else if (seg == 3) { src = wi; dst = owi; n = 3 * Ec * Ec; }
  else               { src = wo; dst = owo; n = Ec * Ec; }
  int base = (blockIdx.x * 256 + threadIdx.x) * 8;
  if (base >= n) return;
  float4 a = *reinterpret_cast<const float4*>(src + base);
  float4 b = *reinterpret_cast<const float4*>(src + base + 4);
  US8 o;
  o.u[0] = f2bf(a.x); o.u[1] = f2bf(a.y); o.u[2] = f2bf(a.z); o.u[3] = f2bf(a.w);
  o.u[4] = f2bf(b.x); o.u[5] = f2bf(b.y); o.u[6] = f2bf(b.z); o.u[7] = f2bf(b.w);
  *reinterpret_cast<US8*>(dst + base) = o;
}

// ---------------------------------------------------------------------------
// K1: QKV projection, bf16 MFMA. (unchanged)
// ---------------------------------------------------------------------------
__global__ __launch_bounds__(256) void k_qkv_mfma(
    const ushortT* __restrict__ xq, const ushortT* __restrict__ xk,
    const ushortT* __restrict__ xv, const ushortT* __restrict__ wi,
    const float* __restrict__ bias, ushortT* __restrict__ qkv)
{
  __shared__ __align__(16) ushortT As[128][LDW];
  __shared__ __align__(16) ushortT Bs[128][LDW];
  const int tid = threadIdx.x;
  const int lane = tid & 63, wid = tid >> 6;
  const int wm = wid >> 1, wn = wid & 1;
  const int li = lane & 15, gi = lane >> 4;
  const int m0 = blockIdx.x * 128, n0 = blockIdx.y * 128;
  const int third = n0 >> 10;
  const ushortT* x = (third == 0) ? xq : (third == 1) ? xk : xv;

  f32x4 acc[4][4] = {};

  for (int k0 = 0; k0 < 1024; k0 += 64) {
    __syncthreads();
#pragma unroll
    for (int i = 0; i < 4; ++i) {
      int c = tid + i * 256;                 // 0..1023
      int row = c >> 3, col = (c & 7) * 8;
      *reinterpret_cast<uint4*>(&As[row][col]) =
          *reinterpret_cast<const uint4*>(x + (size_t)(m0 + row) * 1024 + k0 + col);
      *reinterpret_cast<uint4*>(&Bs[row][col]) =
          *reinterpret_cast<const uint4*>(wi + (size_t)(n0 + row) * 1024 + k0 + col);
    }
    __syncthreads();
#pragma unroll
    for (int ks = 0; ks < 2; ++ks) {
      bf16x8 a[4], b[4];
#pragma unroll
      for (int t = 0; t < 4; ++t) {
        a[t] = *reinterpret_cast<const bf16x8*>(&As[wm * 64 + t * 16 + li][ks * 32 + gi * 8]);
        b[t] = *reinterpret_cast<const bf16x8*>(&Bs[wn * 64 + t * 16 + li][ks * 32 + gi * 8]);
      }
#pragma unroll
      for (int mi = 0; mi < 4; ++mi)
#pragma unroll
        for (int ni = 0; ni < 4; ++ni)
          acc[mi][ni] = MFMA_BF16(a[mi], b[ni], acc[mi][ni], 0, 0, 0);
    }
  }

  const float scale = (third == 0) ? 0.125f : 1.0f;
#pragma unroll
  for (int ni = 0; ni < 4; ++ni) {
    int n = n0 + wn * 64 + ni * 16 + li;
    float bv = bias[n];
    int h = (n >> 6) & 15, d = n & 63;
#pragma unroll
    for (int mi = 0; mi < 4; ++mi)
#pragma unroll
      for (int r = 0; r < 4; ++r) {
        int m = m0 + wm * 64 + mi * 16 + gi * 4 + r;
        int b_ = m >> 10, s = m & 1023;
        size_t o = ((((size_t)third * Bc + b_) * Hc + h) * Sc + s) * Dc + d;
        qkv[o] = f2bf((acc[mi][ni][r] + bv) * scale);
      }
  }
}

// ---------------------------------------------------------------------------
// K2: flash attention, bf16 MFMA. Epilogue now writes a single fused
// offrow[q] = m + ln(l) + ln(16) used by the avg-weights pass.
// ---------------------------------------------------------------------------
__global__ __launch_bounds__(256) void k_flash_mfma(
    const ushortT* __restrict__ qkv, ushortT* __restrict__ ctx,
    float* __restrict__ offrow)
{
  __shared__ __align__(16) ushortT Qs[64][LDW];
  __shared__ __align__(16) ushortT Ks[64][LDW];
  __shared__ __align__(16) ushortT Vt[64][LDW];   // [d][k'] permuted
  __shared__ __align__(16) ushortT Ps[64][LDW];   // [q][k'] permuted
  const int tid = threadIdx.x;
  const int lane = tid & 63, w = tid >> 6;
  const int li = lane & 15, gi = lane >> 4;
  const int s0 = blockIdx.x * 64;
  const int bh = blockIdx.z * Hc + blockIdx.y;
  const ushortT* Q = qkv;
  const ushortT* K = qkv + (size_t)XN;
  const ushortT* V = qkv + (size_t)2 * XN;
  const size_t bhb = (size_t)bh * Sc * Dc;

#pragma unroll
  for (int i = 0; i < 2; ++i) {
    int c = tid + i * 256;
    int row = c >> 3, col = (c & 7) * 8;
    *reinterpret_cast<uint4*>(&Qs[row][col]) =
        *reinterpret_cast<const uint4*>(Q + bhb + (size_t)(s0 + row) * 64 + col);
  }

  f32x4 oa[4] = {};
  float m_r[4], l_r[4];
#pragma unroll
  for (int r = 0; r < 4; ++r) { m_r[r] = -1e30f; l_r[r] = 0.f; }

  // V staging map: pair id vp in [0,32), d-chunk vd0; pair rows (ka, ka+16)
  const int vp = tid & 31;
  const int vd0 = (tid >> 5) * 8;
  const int ka = (vp & 15) + (vp >> 4) * 32;
  const int kpb = 8 * (vp & 15) + 4 * (vp >> 4);  // byte offset of k'-pair in Vt row

  for (int kt = 0; kt < 16; ++kt) {
    const int k0 = kt * 64;
    uint4 kreg[2];
#pragma unroll
    for (int i = 0; i < 2; ++i) {
      int c = tid + i * 256;
      int row = c >> 3, col = (c & 7) * 8;
      kreg[i] = *reinterpret_cast<const uint4*>(K + bhb + (size_t)(k0 + row) * 64 + col);
    }
    uint4 va = *reinterpret_cast<const uint4*>(V + bhb + (size_t)(k0 + ka) * 64 + vd0);
    uint4 vb = *reinterpret_cast<const uint4*>(V + bhb + (size_t)(k0 + ka + 16) * 64 + vd0);
    __syncthreads();   // prior tile's LDS reads complete
#pragma unroll
    for (int i = 0; i < 2; ++i) {
      int c = tid + i * 256;
      int row = c >> 3, col = (c & 7) * 8;
      *reinterpret_cast<uint4*>(&Ks[row][col]) = kreg[i];
    }
    const ushortT* pa_ = reinterpret_cast<const ushortT*>(&va);
    const ushortT* pb_ = reinterpret_cast<const ushortT*>(&vb);
#pragma unroll
    for (int i = 0; i < 8; ++i) {
      unsigned int u = (unsigned int)pa_[i] | ((unsigned int)pb_[i] << 16);
      *reinterpret_cast<unsigned int*>(
          reinterpret_cast<char*>(&Vt[vd0 + i][0]) + kpb) = u;
    }
    __syncthreads();   // staged

    // QK^T
    f32x4 sc[4] = {};
#pragma unroll
    for (int ds = 0; ds < 2; ++ds) {
      bf16x8 aq = *reinterpret_cast<const bf16x8*>(&Qs[w * 16 + li][ds * 32 + gi * 8]);
#pragma unroll
      for (int nf = 0; nf < 4; ++nf) {
        bf16x8 bk = *reinterpret_cast<const bf16x8*>(&Ks[nf * 16 + li][ds * 32 + gi * 8]);
        sc[nf] = MFMA_BF16(aq, bk, sc[nf], 0, 0, 0);
      }
    }

    // online softmax (wave-local; rows r live in acc component r)
    float esc[4];
#pragma unroll
    for (int r = 0; r < 4; ++r) {
      float v = fmaxf(fmaxf(sc[0][r], sc[1][r]), fmaxf(sc[2][r], sc[3][r]));
      v = fmaxf(v, __shfl_xor(v, 1));
      v = fmaxf(v, __shfl_xor(v, 2));
      v = fmaxf(v, __shfl_xor(v, 4));
      v = fmaxf(v, __shfl_xor(v, 8));
      float mnew = fmaxf(m_r[r], v);
      esc[r] = __expf(m_r[r] - mnew);
      m_r[r] = mnew;
    }
    float p[4][4];
#pragma unroll
    for (int r = 0; r < 4; ++r) {
      float s = 0.f;
#pragma unroll
      for (int nf = 0; nf < 4; ++nf) { p[nf][r] = __expf(sc[nf][r] - m_r[r]); s += p[nf][r]; }
      s += __shfl_xor(s, 1); s += __shfl_xor(s, 2);
      s += __shfl_xor(s, 4); s += __shfl_xor(s, 8);
      l_r[r] = l_r[r] * esc[r] + s;
#pragma unroll
      for (int nf = 0; nf < 4; ++nf) oa[nf][r] *= esc[r];
    }
    // pack P (bf16) into Ps rows (wave-private): cols k' = 4*li + nf
#pragma unroll
    for (int r = 0; r < 4; ++r) {
      unsigned int u0 = (unsigned int)f2bf(p[0][r]) | ((unsigned int)f2bf(p[1][r]) << 16);
      unsigned int u1 = (unsigned int)f2bf(p[2][r]) | ((unsigned int)f2bf(p[3][r]) << 16);
      uint2 uu; uu.x = u0; uu.y = u1;
      *reinterpret_cast<uint2*>(
          reinterpret_cast<char*>(&Ps[w * 16 + gi * 4 + r][0]) + li * 8) = uu;
    }
    // PV (contraction over permuted k'; P and Vt use the same permutation)
#pragma unroll
    for (int ks = 0; ks < 2; ++ks) {
      bf16x8 pa = *reinterpret_cast<const bf16x8*>(&Ps[w * 16 + li][ks * 32 + gi * 8]);
#pragma unroll
      for (int nf = 0; nf < 4; ++nf) {
        bf16x8 vv = *reinterpret_cast<const bf16x8*>(&Vt[nf * 16 + li][ks * 32 + gi * 8]);
        oa[nf] = MFMA_BF16(pa, vv, oa[nf], 0, 0, 0);
      }
    }
  }

  float inv[4];
#pragma unroll
  for (int r = 0; r < 4; ++r) inv[r] = 1.0f / l_r[r];
#pragma unroll
  for (int nf = 0; nf < 4; ++nf)
#pragma unroll
    for (int r = 0; r < 4; ++r) {
      int q = s0 + w * 16 + gi * 4 + r;
      ctx[bhb + (size_t)q * 64 + nf * 16 + li] = f2bf(oa[nf][r] * inv[r]);
    }
  if (li == 0) {
#pragma unroll
    for (int r = 0; r < 4; ++r) {
      int q = s0 + w * 16 + gi * 4 + r;
      // fused softmax offset: exp(s - off) = exp(s - m) / (16 * l)
      offrow[(size_t)bh * Sc + q] = m_r[r] + __logf(l_r[r]) + 2.77258872f;
    }
  }
}

// ---------------------------------------------------------------------------
// K3: out projection, bf16 MFMA. (unchanged)
// ---------------------------------------------------------------------------
__global__ __launch_bounds__(256) void k_outproj_mfma(
    const ushortT* __restrict__ ctx, const ushortT* __restrict__ wo,
    const float* __restrict__ bias, float* __restrict__ out)
{
  __shared__ __align__(16) ushortT As[128][LDW];
  __shared__ __align__(16) ushortT Bs[128][LDW];
  const int tid = threadIdx.x;
  const int lane = tid & 63, wid = tid >> 6;
  const int wm = wid >> 1, wn = wid & 1;
  const int li = lane & 15, gi = lane >> 4;
  const int m0 = blockIdx.x * 128, n0 = blockIdx.y * 128;

  f32x4 acc[4][4] = {};

  for (int k0 = 0; k0 < 1024; k0 += 64) {
    const int h = k0 >> 6;          // BK==Dc: one head per K-step
    __syncthreads();
#pragma unroll
    for (int i = 0; i < 4; ++i) {
      int c = tid + i * 256;
      int row = c >> 3, col = (c & 7) * 8;    // col < 64 == within head
      int m = m0 + row;
      int b_ = m >> 10, s = m & 1023;
      *reinterpret_cast<uint4*>(&As[row][col]) =
          *reinterpret_cast<const uint4*>(
              ctx + (((size_t)b_ * Hc + h) * Sc + s) * Dc + col);
      *reinterpret_cast<uint4*>(&Bs[row][col]) =
          *reinterpret_cast<const uint4*>(wo + (size_t)(n0 + row) * 1024 + k0 + col);
    }
    __syncthreads();
#pragma unroll
    for (int ks = 0; ks < 2; ++ks) {
      bf16x8 a[4], b[4];
#pragma unroll
      for (int t = 0; t < 4; ++t) {
        a[t] = *reinterpret_cast<const bf16x8*>(&As[wm * 64 + t * 16 + li][ks * 32 + gi * 8]);
        b[t] = *reinterpret_cast<const bf16x8*>(&Bs[wn * 64 + t * 16 + li][ks * 32 + gi * 8]);
      }
#pragma unroll
      for (int mi = 0; mi < 4; ++mi)
#pragma unroll
        for (int ni = 0; ni < 4; ++ni)
          acc[mi][ni] = MFMA_BF16(a[mi], b[ni], acc[mi][ni], 0, 0, 0);
    }
  }

#pragma unroll
  for (int ni = 0; ni < 4; ++ni) {
    int n = n0 + wn * 64 + ni * 16 + li;
    float bv = bias[n];
#pragma unroll
    for (int mi = 0; mi < 4; ++mi)
#pragma unroll
      for (int r = 0; r < 4; ++r) {
        int m = m0 + wm * 64 + mi * 16 + gi * 4 + r;
        out[(size_t)m * 1024 + n] = acc[mi][ni][r] + bv;
      }
  }
}

// ---------------------------------------------------------------------------
// K4: head-averaged attention weights * gate (unnormalized), bf16 MFMA.
// No LDS. __launch_bounds__(256,4): grid gives only 4 blocks/CU, so allow
// ~128 VGPRs for in-flight loads (VGPR=48 before = serialized head loop).
// Manual 2x head unroll for ILP. avg = sum_h exp(s_h - off_h) with
// off = m + ln(l) + ln16 precomputed by k_flash (no per-head div/rcp).
// ---------------------------------------------------------------------------
__global__ __launch_bounds__(256, 4) void k_avggate_mfma(
    const ushortT* __restrict__ qkv, const float* __restrict__ offrow,
    const float* __restrict__ gate, float* __restrict__ out1)
{
  const int tid = threadIdx.x;
  const int lane = tid & 63, w = tid >> 6;
  const int li = lane & 15, gi = lane >> 4;
  const int c0 = blockIdx.x * 64;
  const int s0 = blockIdx.y * 64;
  const int b = blockIdx.z;
  const ushortT* Q = qkv;
  const ushortT* K = qkv + (size_t)XN;

  const int qrow = s0 + w * 16 + li;          // A-frag row (per lane)
  const int qoff = s0 + w * 16 + gi * 4;      // C/D rows (per lane, 4 consecutive)
  f32x4 avg[4] = {};

  for (int h = 0; h < Hc; h += 2) {
    const size_t bh0 = ((size_t)b * Hc + h) * Sc;
    const size_t bh1 = bh0 + Sc;
    const ushortT* Qb0 = Q + bh0 * Dc;
    const ushortT* Kb0 = K + bh0 * Dc;
    const ushortT* Qb1 = Q + bh1 * Dc;
    const ushortT* Kb1 = K + bh1 * Dc;

    float4 of0 = *reinterpret_cast<const float4*>(offrow + bh0 + qoff);
    float4 of1 = *reinterpret_cast<const float4*>(offrow + bh1 + qoff);
    float ofa0[4] = {of0.x, of0.y, of0.z, of0.w};
    float ofa1[4] = {of1.x, of1.y, of1.z, of1.w};

    bf16x8 aq0[2], aq1[2];
#pragma unroll
    for (int ds = 0; ds < 2; ++ds) {
      aq0[ds] = *reinterpret_cast<const bf16x8*>(Qb0 + (size_t)qrow * 64 + ds * 32 + gi * 8);
      aq1[ds] = *reinterpret_cast<const bf16x8*>(Qb1 + (size_t)qrow * 64 + ds * 32 + gi * 8);
    }

    f32x4 sc0[4] = {}, sc1[4] = {};
#pragma unroll
    for (int ds = 0; ds < 2; ++ds) {
      bf16x8 bk0[4], bk1[4];
#pragma unroll
      for (int nf = 0; nf < 4; ++nf) {
        bk0[nf] = *reinterpret_cast<const bf16x8*>(
            Kb0 + (size_t)(c0 + nf * 16 + li) * 64 + ds * 32 + gi * 8);
        bk1[nf] = *reinterpret_cast<const bf16x8*>(
            Kb1 + (size_t)(c0 + nf * 16 + li) * 64 + ds * 32 + gi * 8);
      }
#pragma unroll
      for (int nf = 0; nf < 4; ++nf) sc0[nf] = MFMA_BF16(aq0[ds], bk0[nf], sc0[nf], 0, 0, 0);
#pragma unroll
      for (int nf = 0; nf < 4; ++nf) sc1[nf] = MFMA_BF16(aq1[ds], bk1[nf], sc1[nf], 0, 0, 0);
    }

#pragma unroll
    for (int nf = 0; nf < 4; ++nf)
#pragma unroll
      for (int r = 0; r < 4; ++r) {
        avg[nf][r] += __expf(sc0[nf][r] - ofa0[r]);
        avg[nf][r] += __expf(sc1[nf][r] - ofa1[r]);
      }
  }

#pragma unroll
  for (int nf = 0; nf < 4; ++nf)
#pragma unroll
    for (int r = 0; r < 4; ++r) {
      int q = qoff + r;
      size_t o = ((size_t)b * Sc + q) * Sc + c0 + nf * 16 + li;
      out1[o] = avg[nf][r] * gate[o];
    }
}

// ---------------------------------------------------------------------------
// K5: in-place row renormalization: x / (sum(x) + 1e-12)
// ---------------------------------------------------------------------------
__global__ __launch_bounds__(256) void k_renorm(float* __restrict__ out1)
{
  __shared__ float wsum[4];
  const int tid = threadIdx.x;
  float* row = out1 + (size_t)blockIdx.x * Sc;
  float4 v = *reinterpret_cast<const float4*>(row + tid * 4);
  float s = v.x + v.y + v.z + v.w;
#pragma unroll
  for (int off = 1; off < 64; off <<= 1) s += __shfl_xor(s, off);
  if ((tid & 63) == 0) wsum[tid >> 6] = s;
  __syncthreads();
  float inv = 1.0f / (wsum[0] + wsum[1] + wsum[2] + wsum[3] + 1e-12f);
  v.x *= inv; v.y *= inv; v.z *= inv; v.w *= inv;
  *reinterpret_cast<float4*>(row + tid * 4) = v;
}

// ---------------------------------------------------------------------------
extern "C" void kernel_launch(void* const* d_in, const int* in_sizes, int n_in,
                              void* d_out, int out_size, void* d_ws, size_t ws_size,
                              hipStream_t stream) {
  const float* query = (const float*)d_in[0];
  const float* key   = (const float*)d_in[1];
  const float* value = (const float*)d_in[2];
  const float* gate  = (const float*)d_in[3];
  const float* w_in  = (const float*)d_in[4];
  const float* b_in  = (const float*)d_in[5];
  const float* w_out = (const float*)d_in[6];
  const float* b_out = (const float*)d_in[7];

  float* out0 = (float*)d_out;                       // attn_output (B,S,E)
  float* out1 = out0 + (size_t)Bc * Sc * Ec;         // gated (B,S,S)

  // bf16 workspace layout (ushort elements)
  ushortT* xq   = (ushortT*)d_ws;                    // 4M
  ushortT* xk   = xq + (size_t)XN;                   // 4M
  ushortT* xv   = xk + (size_t)XN;                   // 4M
  ushortT* wi   = xv + (size_t)XN;                   // 3M
  ushortT* wo   = wi + (size_t)3 * Ec * Ec;          // 1M
  ushortT* qkvb = wo + (size_t)Ec * Ec;              // 12M (3,B,H,S,D)
  ushortT* ctxb = xq;                                // alias: xq dead after k_qkv
  float* offrow = (float*)(qkvb + (size_t)3 * XN);   // 64K (m + ln l + ln 16)

  hipLaunchKernelGGL(k_cast, dim3(2048, 5), dim3(256), 0, stream,
                     query, key, value, w_in, w_out, xq, xk, xv, wi, wo);
  hipLaunchKernelGGL(k_qkv_mfma, dim3(32, 24), dim3(256), 0, stream,
                     xq, xk, xv, wi, b_in, qkvb);
  hipLaunchKernelGGL(k_flash_mfma, dim3(16, 16, 4), dim3(256), 0, stream,
                     qkvb, ctxb, offrow);
  hipLaunchKernelGGL(k_outproj_mfma, dim3(32, 8), dim3(256), 0, stream,
                     ctxb, wo, b_out, out0);
  hipLaunchKernelGGL(k_avggate_mfma, dim3(16, 16, 4), dim3(256), 0, stream,
                     qkvb, offrow, gate, out1);
  hipLaunchKernelGGL(k_renorm, dim3(Bc * Sc), dim3(256), 0, stream, out1);
}